// Round 1
// baseline (2576.025 us; speedup 1.0000x reference)
//
#include <hip/hip_runtime.h>
#include <hip/hip_bf16.h>
#include <math.h>

// MoE: B=4,S=2048 -> T=8192 tokens, D=2048, E=8 experts, F=2048, top-2.
#define T_TOK 8192
#define DDIM  2048
#define NEXP  8
#define FDIM  2048
#define BK    32
#define NT    64          // K / BK for both GEMMs (2048/32)

typedef __bf16 bf16x8 __attribute__((ext_vector_type(8)));
typedef float  f32x4  __attribute__((ext_vector_type(4)));

#define MFMA16(a, b, c) __builtin_amdgcn_mfma_f32_16x16x32_bf16((a), (b), (c), 0, 0, 0)

// async global->LDS, 16B per lane; LDS dest = wave-uniform base + lane*16
#define GLDS16(g, l)                                                            \
  __builtin_amdgcn_global_load_lds(                                             \
      (const __attribute__((address_space(1))) void*)(g),                       \
      (__attribute__((address_space(3))) void*)(l), 16, 0, 0)

__device__ __forceinline__ unsigned short f2bf(float f) {
  unsigned int u = __builtin_bit_cast(unsigned int, f);
  u += 0x7fffu + ((u >> 16) & 1u);
  return (unsigned short)(u >> 16);
}

// ---------------- fp32 -> bf16 bulk convert (8 elems/thread, grid-stride) ----
__global__ __launch_bounds__(256) void k_cvt(const float* __restrict__ src,
                                             unsigned short* __restrict__ dst,
                                             long n) {
  long i = ((long)blockIdx.x * 256 + threadIdx.x) * 8;
  long stride = (long)gridDim.x * 256 * 8;
  for (; i < n; i += stride) {
    float4 f0 = *(const float4*)(src + i);
    float4 f1 = *(const float4*)(src + i + 4);
    union { unsigned short u[8]; int4 v; } pk;
    pk.u[0] = f2bf(f0.x); pk.u[1] = f2bf(f0.y); pk.u[2] = f2bf(f0.z); pk.u[3] = f2bf(f0.w);
    pk.u[4] = f2bf(f1.x); pk.u[5] = f2bf(f1.y); pk.u[6] = f2bf(f1.z); pk.u[7] = f2bf(f1.w);
    *(int4*)(dst + i) = pk.v;
  }
}

// ---- w1/w3 -> interleaved w13 bf16. For f-block of 16: 16 rows of w1 (gate)
// then 16 rows of w3 (up). dst row = e*4096 + (f>>4)*32 + 16*is_up + (f&15).
__global__ __launch_bounds__(256) void k_cvt13(const float* __restrict__ w1,
                                               const float* __restrict__ w3,
                                               unsigned short* __restrict__ dst) {
  const long n = (long)NEXP * FDIM * DDIM;
  long i = ((long)blockIdx.x * 256 + threadIdx.x) * 8;
  long stride = (long)gridDim.x * 256 * 8;
  for (; i < n; i += stride) {
    long frow = i >> 11;            // e*F + f
    int  col  = (int)(i & 2047);
    int  e    = (int)(frow >> 11);
    int  f    = (int)(frow & 2047);
    long drow = (long)e * 4096 + (long)(f >> 4) * 32 + (f & 15);
    {
      float4 a0 = *(const float4*)(w1 + i);
      float4 a1 = *(const float4*)(w1 + i + 4);
      union { unsigned short u[8]; int4 v; } pk;
      pk.u[0] = f2bf(a0.x); pk.u[1] = f2bf(a0.y); pk.u[2] = f2bf(a0.z); pk.u[3] = f2bf(a0.w);
      pk.u[4] = f2bf(a1.x); pk.u[5] = f2bf(a1.y); pk.u[6] = f2bf(a1.z); pk.u[7] = f2bf(a1.w);
      *(int4*)(dst + (drow << 11) + col) = pk.v;
    }
    {
      float4 a0 = *(const float4*)(w3 + i);
      float4 a1 = *(const float4*)(w3 + i + 4);
      union { unsigned short u[8]; int4 v; } pk;
      pk.u[0] = f2bf(a0.x); pk.u[1] = f2bf(a0.y); pk.u[2] = f2bf(a0.z); pk.u[3] = f2bf(a0.w);
      pk.u[4] = f2bf(a1.x); pk.u[5] = f2bf(a1.y); pk.u[6] = f2bf(a1.z); pk.u[7] = f2bf(a1.w);
      *(int4*)(dst + ((drow + 16) << 11) + col) = pk.v;
    }
  }
}

// ---------------- router: fp32 logits -> softmax -> top2 ----------------
__global__ __launch_bounds__(256) void k_router(
    const float* __restrict__ x, const float* __restrict__ gw,
    int* __restrict__ cnt, int* __restrict__ topk_e, float* __restrict__ topk_w) {
  int lane = threadIdx.x & 63;
  int wave = threadIdx.x >> 6;
  int t = blockIdx.x * 4 + wave;
  const float* xr = x + (size_t)t * DDIM;
  float acc[NEXP];
#pragma unroll
  for (int e = 0; e < NEXP; e++) acc[e] = 0.f;
  for (int j = lane; j < DDIM; j += 64) {
    float xv = xr[j];
#pragma unroll
    for (int e = 0; e < NEXP; e++) acc[e] += xv * gw[e * DDIM + j];
  }
#pragma unroll
  for (int e = 0; e < NEXP; e++) {
    for (int off = 32; off > 0; off >>= 1) acc[e] += __shfl_down(acc[e], off, 64);
  }
  if (lane == 0) {
    float m = acc[0];
#pragma unroll
    for (int e = 1; e < NEXP; e++) m = fmaxf(m, acc[e]);
    float p[NEXP]; float s = 0.f;
#pragma unroll
    for (int e = 0; e < NEXP; e++) { p[e] = expf(acc[e] - m); s += p[e]; }
    float inv = 1.f / s;
    int e1 = 0; float v1 = p[0];
#pragma unroll
    for (int e = 1; e < NEXP; e++) if (p[e] > v1) { v1 = p[e]; e1 = e; }
    int e2 = -1; float v2 = -1.f;
#pragma unroll
    for (int e = 0; e < NEXP; e++) {
      if (e == e1) continue;
      if (p[e] > v2) { v2 = p[e]; e2 = e; }
    }
    topk_e[t * 2 + 0] = e1; topk_w[t * 2 + 0] = v1 * inv;
    topk_e[t * 2 + 1] = e2; topk_w[t * 2 + 1] = v2 * inv;
    atomicAdd(&cnt[e1], 1);
    atomicAdd(&cnt[e2], 1);
  }
}

__global__ void k_scan(const int* __restrict__ cnt, int* __restrict__ prefix) {
  if (threadIdx.x == 0 && blockIdx.x == 0) {
    int s = 0;
    for (int e = 0; e < NEXP; e++) { prefix[e] = s; s += cnt[e]; }
    prefix[NEXP] = s;
  }
}

__global__ __launch_bounds__(256) void k_assign(
    const int* __restrict__ topk_e, const float* __restrict__ topk_w,
    const int* __restrict__ prefix, int* __restrict__ fill,
    int* __restrict__ toks, float* __restrict__ rwc) {
  int t = blockIdx.x * 256 + threadIdx.x;
  if (t >= T_TOK) return;
#pragma unroll
  for (int k = 0; k < 2; k++) {
    int e = topk_e[t * 2 + k];
    float w = topk_w[t * 2 + k];
    int pos = atomicAdd(&fill[e], 1);
    int slot = prefix[e] + pos;
    toks[slot] = t;
    rwc[slot] = w;
  }
}

// =====================================================================
// 256x256-tile pipelined GEMMs. 512 threads = 8 waves (2 M-halves x 4 N-quarters),
// per-wave 128x64 output (acc[8][4] f32x4). BK=32, ring of 4 LDS buffers
// (4 x (A 16KB | B 16KB) = 128 KB): while computing tile t, stage tile t+3;
// end-of-tile wait is a COUNTED s_waitcnt vmcnt(8) (2 tiles in flight), never 0.
//
// LDS layout (per tensor, per buffer): 128 lines x 128 B; line lr holds
// M-rows {2lr, 2lr+1}; bytes within a line are XOR-permuted by ((lr&7)<<4).
// global_load_lds writes linearly (wave base + lane*16); the swizzle is
// applied by pre-permuting the per-lane GLOBAL source (row/col recovered from
// g = laneByte ^ ((lr&7)<<4): row = 2lr + (g>>6), colByte = g&63). Frag reads
// XOR the same pattern -> 2-way residual bank conflict (free).
// =====================================================================

__global__ __launch_bounds__(512, 2) void k_gemm1(
    const unsigned short* __restrict__ xb, const unsigned short* __restrict__ w13b,
    const int* __restrict__ cnt, const int* __restrict__ prefix,
    const int* __restrict__ toks, unsigned short* __restrict__ hbuf) {
  int e  = blockIdx.x >> 6;
  int mb = blockIdx.x & 63;
  int ne = cnt[e];
  if (mb * 256 >= ne) return;
  int base = prefix[e];
  int nb = blockIdx.y;                    // 16 n-blocks over N=4096 (w13)

  __shared__ __align__(16) unsigned short smem[4 * 16384];  // 128 KB
  __shared__ int ltok[256];

  int tid = threadIdx.x;
  if (tid < 256) {
    int i = mb * 256 + tid;
    ltok[tid] = (i < ne) ? toks[base + i] : toks[base + ne - 1];
  }
  __syncthreads();

  int l = tid & 63, w = tid >> 6;
  int wm = w >> 2, wn = w & 3;
  int fr = l & 15, q = l >> 4;

  // frag-read offsets (ushort units): line = .. + (fr>>1); in-line swizzle
  int rdSwz = (((fr & 1) * 32) + q * 8) ^ ((fr >> 1) * 8);
  const int aRd = (wm * 64 + (fr >> 1)) * 64 + rdSwz;           // + sm*512
  const int bRd = 8192 + (wn * 32 + (fr >> 1)) * 64 + rdSwz;    // + sn*512

  // staging: sweep s covers lines s*64 + w*8 + (l>>3)
  int lr0 = w * 8 + (l >> 3);
  int gbyte = ((l & 7) * 16) ^ ((l >> 3) << 4);  // permuted byte within line
  int kel = (gbyte & 63) >> 1;                   // element col offset
  int hi  = gbyte >> 6;                          // which row of the pair
  const unsigned short* gA[2];
  const unsigned short* gB[2];
  int ldsA[2], ldsB[2];
#pragma unroll
  for (int s = 0; s < 2; s++) {
    int mr = s * 128 + 2 * lr0 + hi;             // row within 256-row tile
    gA[s] = xb + (size_t)ltok[mr] * DDIM + kel;
    gB[s] = w13b + ((size_t)(e * 4096 + nb * 256 + mr)) * DDIM + kel;
    ldsA[s] = (s * 64 + w * 8) * 64;
    ldsB[s] = 8192 + (s * 64 + w * 8) * 64;
  }

#define STAGE1(tt, s)                                                   \
  { int bo_ = ((tt) & 3) * 16384;                                       \
    GLDS16(gA[s] + (size_t)(tt) * BK, smem + bo_ + ldsA[s]);            \
    GLDS16(gB[s] + (size_t)(tt) * BK, smem + bo_ + ldsB[s]); }

  f32x4 acc[8][4];
#pragma unroll
  for (int i = 0; i < 8; i++)
#pragma unroll
    for (int j = 0; j < 4; j++) acc[i][j] = (f32x4){0, 0, 0, 0};

  // prologue: stage tiles 0,1,2; wait tile 0 (8 = 2 tiles outstanding)
  STAGE1(0, 0); STAGE1(0, 1);
  STAGE1(1, 0); STAGE1(1, 1);
  STAGE1(2, 0); STAGE1(2, 1);
  asm volatile("s_waitcnt vmcnt(8)" ::: "memory");
  __builtin_amdgcn_s_barrier();

#pragma unroll 1
  for (int t = 0; t < NT; ++t) {
    const unsigned short* sb = smem + (t & 3) * 16384;
    bf16x8 af[4], bfr[4];
    // ---- phase 0: m-frags 0..3 x all n
#pragma unroll
    for (int i = 0; i < 4; i++) af[i] = *(const bf16x8*)(sb + aRd + i * 512);
#pragma unroll
    for (int j = 0; j < 4; j++) bfr[j] = *(const bf16x8*)(sb + bRd + j * 512);
    if (t + 3 < NT) STAGE1(t + 3, 0);
    __builtin_amdgcn_s_barrier();
    asm volatile("s_waitcnt lgkmcnt(0)" ::: "memory");
    __builtin_amdgcn_sched_barrier(0);
    __builtin_amdgcn_s_setprio(1);
#pragma unroll
    for (int i = 0; i < 4; i++)
#pragma unroll
      for (int j = 0; j < 4; j++) acc[i][j] = MFMA16(af[i], bfr[j], acc[i][j]);
    __builtin_amdgcn_s_setprio(0);
    __builtin_amdgcn_s_barrier();
    // ---- phase 1: m-frags 4..7 x all n (B reused)
#pragma unroll
    for (int i = 0; i < 4; i++) af[i] = *(const bf16x8*)(sb + aRd + (4 + i) * 512);
    if (t + 3 < NT) STAGE1(t + 3, 1);
    __builtin_amdgcn_s_barrier();
    asm volatile("s_waitcnt lgkmcnt(0)" ::: "memory");
    __builtin_amdgcn_sched_barrier(0);
    __builtin_amdgcn_s_setprio(1);
#pragma unroll
    for (int i = 0; i < 4; i++)
#pragma unroll
      for (int j = 0; j < 4; j++) acc[4 + i][j] = MFMA16(af[i], bfr[j], acc[4 + i][j]);
    __builtin_amdgcn_s_setprio(0);
    // ---- tile end: counted drain (next tile landed; 2 tiles stay in flight)
    int rem = NT - 2 - t;
    if (rem >= 2)      { asm volatile("s_waitcnt vmcnt(8)" ::: "memory"); }
    else if (rem == 1) { asm volatile("s_waitcnt vmcnt(4)" ::: "memory"); }
    else if (rem == 0) { asm volatile("s_waitcnt vmcnt(0)" ::: "memory"); }
    if (t + 1 < NT) __builtin_amdgcn_s_barrier();
  }
#undef STAGE1

  // epilogue: even n-frag = gate, odd = up, same f-columns, same lanes
#pragma unroll
  for (int sm = 0; sm < 8; sm++) {
    int row0 = mb * 256 + wm * 128 + sm * 16 + q * 4;
#pragma unroll
    for (int p = 0; p < 2; p++) {
      int fcol = ((nb << 3) + (wn << 1) + p) * 16 + fr;
#pragma unroll
      for (int j = 0; j < 4; j++) {
        int row = row0 + j;
        if (row < ne) {
          float g = acc[sm][2 * p][j];
          float u = acc[sm][2 * p + 1][j];
          float h = (g / (1.f + expf(-g))) * u;
          hbuf[(size_t)(base + row) * FDIM + fcol] = f2bf(h);
        }
      }
    }
  }
}

__global__ __launch_bounds__(512, 2) void k_gemm2(
    const unsigned short* __restrict__ hbuf, const unsigned short* __restrict__ w2b,
    const int* __restrict__ cnt, const int* __restrict__ prefix,
    const int* __restrict__ toks, const float* __restrict__ rwc,
    float* __restrict__ y) {
  int e  = blockIdx.x >> 6;
  int mb = blockIdx.x & 63;
  int ne = cnt[e];
  if (mb * 256 >= ne) return;
  int base = prefix[e];
  int nb = blockIdx.y;                    // 8 n-blocks over D=2048

  __shared__ __align__(16) unsigned short smem[4 * 16384];  // 128 KB
  __shared__ int ltok[256];
  __shared__ float lrw[256];

  int tid = threadIdx.x;
  if (tid < 256) {
    int i = mb * 256 + tid;
    int ok = (i < ne);
    ltok[tid] = ok ? toks[base + i] : 0;
    lrw[tid]  = ok ? rwc[base + i] : 0.f;
  }
  __syncthreads();

  int l = tid & 63, w = tid >> 6;
  int wm = w >> 2, wn = w & 3;
  int fr = l & 15, q = l >> 4;

  int rdSwz = (((fr & 1) * 32) + q * 8) ^ ((fr >> 1) * 8);
  const int aRd = (wm * 64 + (fr >> 1)) * 64 + rdSwz;
  const int bRd = 8192 + (wn * 32 + (fr >> 1)) * 64 + rdSwz;

  int lr0 = w * 8 + (l >> 3);
  int gbyte = ((l & 7) * 16) ^ ((l >> 3) << 4);
  int kel = (gbyte & 63) >> 1;
  int hi  = gbyte >> 6;
  const unsigned short* gA[2];
  const unsigned short* gB[2];
  int ldsA[2], ldsB[2];
#pragma unroll
  for (int s = 0; s < 2; s++) {
    int mr = s * 128 + 2 * lr0 + hi;
    int mrc = mb * 256 + mr; if (mrc >= ne) mrc = ne - 1;   // clamp: no pad rows needed
    gA[s] = hbuf + (size_t)(base + mrc) * FDIM + kel;
    gB[s] = w2b + ((size_t)(e * 2048 + nb * 256 + mr)) * FDIM + kel;
    ldsA[s] = (s * 64 + w * 8) * 64;
    ldsB[s] = 8192 + (s * 64 + w * 8) * 64;
  }

#define STAGE2(tt, s)                                                   \
  { int bo_ = ((tt) & 3) * 16384;                                       \
    GLDS16(gA[s] + (size_t)(tt) * BK, smem + bo_ + ldsA[s]);            \
    GLDS16(gB[s] + (size_t)(tt) * BK, smem + bo_ + ldsB[s]); }

  f32x4 acc[8][4];
#pragma unroll
  for (int i = 0; i < 8; i++)
#pragma unroll
    for (int j = 0; j < 4; j++) acc[i][j] = (f32x4){0, 0, 0, 0};

  STAGE2(0, 0); STAGE2(0, 1);
  STAGE2(1, 0); STAGE2(1, 1);
  STAGE2(2, 0); STAGE2(2, 1);
  asm volatile("s_waitcnt vmcnt(8)" ::: "memory");
  __builtin_amdgcn_s_barrier();

#pragma unroll 1
  for (int t = 0; t < NT; ++t) {
    const unsigned short* sb = smem + (t & 3) * 16384;
    bf16x8 af[4], bfr[4];
#pragma unroll
    for (int i = 0; i < 4; i++) af[i] = *(const bf16x8*)(sb + aRd + i * 512);
#pragma unroll
    for (int j = 0; j < 4; j++) bfr[j] = *(const bf16x8*)(sb + bRd + j * 512);
    if (t + 3 < NT) STAGE2(t + 3, 0);
    __builtin_amdgcn_s_barrier();
    asm volatile("s_waitcnt lgkmcnt(0)" ::: "memory");
    __builtin_amdgcn_sched_barrier(0);
    __builtin_amdgcn_s_setprio(1);
#pragma unroll
    for (int i = 0; i < 4; i++)
#pragma unroll
      for (int j = 0; j < 4; j++) acc[i][j] = MFMA16(af[i], bfr[j], acc[i][j]);
    __builtin_amdgcn_s_setprio(0);
    __builtin_amdgcn_s_barrier();
#pragma unroll
    for (int i = 0; i < 4; i++) af[i] = *(const bf16x8*)(sb + aRd + (4 + i) * 512);
    if (t + 3 < NT) STAGE2(t + 3, 1);
    __builtin_amdgcn_s_barrier();
    asm volatile("s_waitcnt lgkmcnt(0)" ::: "memory");
    __builtin_amdgcn_sched_barrier(0);
    __builtin_amdgcn_s_setprio(1);
#pragma unroll
    for (int i = 0; i < 4; i++)
#pragma unroll
      for (int j = 0; j < 4; j++) acc[4 + i][j] = MFMA16(af[i], bfr[j], acc[4 + i][j]);
    __builtin_amdgcn_s_setprio(0);
    int rem = NT - 2 - t;
    if (rem >= 2)      { asm volatile("s_waitcnt vmcnt(8)" ::: "memory"); }
    else if (rem == 1) { asm volatile("s_waitcnt vmcnt(4)" ::: "memory"); }
    else if (rem == 0) { asm volatile("s_waitcnt vmcnt(0)" ::: "memory"); }
    if (t + 1 < NT) __builtin_amdgcn_s_barrier();
  }
#undef STAGE2

#pragma unroll
  for (int sm = 0; sm < 8; sm++) {
    int lrow0 = wm * 128 + sm * 16 + q * 4;
#pragma unroll
    for (int j = 0; j < 4; j++) {
      int row = mb * 256 + lrow0 + j;
      if (row < ne) {
        int tok = ltok[lrow0 + j];
        float wgt = lrw[lrow0 + j];
        float* yr = y + (size_t)tok * DDIM;
#pragma unroll
        for (int sn = 0; sn < 4; sn++) {
          int col = (nb << 8) + (wn << 6) + (sn << 4) + fr;
          atomicAdd(yr + col, acc[sm][sn][j] * wgt);
        }
      }
    }
  }
}

// ---------------- launch ----------------
// ws layout (bytes), 16B-aligned chunks:
//   0          cnt[8] / 256 fill[8] / 512 prefix[9]
//   1024       topk_e[16384]            (64 KiB)
//   66560      topk_w[16384]            (64 KiB)
//   132096     toks[16384]              (64 KiB)
//   197632     rwc[16384]               (64 KiB)
//   263168     hbuf: 16384 x 2048 bf16  (67.1 MB; A-side reads are clamped, no pad)
//   67372032   w13b bf16 (interleaved)  (134.2 MB)
//   201589760  w2b bf16                 (67.1 MB)
//   268698624  xb  bf16                 (33.6 MB)   total ~302.3 MB
extern "C" void kernel_launch(void* const* d_in, const int* in_sizes, int n_in,
                              void* d_out, int out_size, void* d_ws, size_t ws_size,
                              hipStream_t stream) {
  const float* x  = (const float*)d_in[0];
  const float* gw = (const float*)d_in[1];
  const float* w1 = (const float*)d_in[2];
  const float* w3 = (const float*)d_in[3];
  const float* w2 = (const float*)d_in[4];
  float* y = (float*)d_out;

  char* ws = (char*)d_ws;
  int*   cnt    = (int*)(ws + 0);
  int*   fill   = (int*)(ws + 256);
  int*   prefix = (int*)(ws + 512);
  int*   topk_e = (int*)(ws + 1024);
  float* topk_w = (float*)(ws + 66560);
  int*   toks   = (int*)(ws + 132096);
  float* rwc    = (float*)(ws + 197632);
  unsigned short* hbuf = (unsigned short*)(ws + 263168);
  unsigned short* w13b = (unsigned short*)(ws + 67372032UL);
  unsigned short* w2b  = (unsigned short*)(ws + 201589760UL);
  unsigned short* xb   = (unsigned short*)(ws + 268698624UL);

  const long NW = (long)NEXP * FDIM * DDIM;   // 33.55M per weight tensor
  const long NX = (long)T_TOK * DDIM;         // 16.78M

  hipMemsetAsync(ws, 0, 1024, stream);
  hipMemsetAsync(d_out, 0, (size_t)out_size * sizeof(float), stream);

  k_cvt13<<<1024, 256, 0, stream>>>(w1, w3, w13b);
  k_cvt<<<1024, 256, 0, stream>>>(w2, w2b, NW);
  k_cvt<<<1024, 256, 0, stream>>>(x,  xb,  NX);

  k_router<<<T_TOK / 4, 256, 0, stream>>>(x, gw, cnt, topk_e, topk_w);
  k_scan<<<1, 64, 0, stream>>>(cnt, prefix);
  k_assign<<<T_TOK / 256, 256, 0, stream>>>(topk_e, topk_w, prefix, fill, toks, rwc);

  k_gemm1<<<dim3(NEXP * 64, FDIM * 2 / 256), 512, 0, stream>>>(xb, w13b, cnt, prefix, toks, hbuf);
  k_gemm2<<<dim3(NEXP * 64, DDIM / 256), 512, 0, stream>>>(hbuf, w2b, cnt, prefix, toks, rwc, y);
}

// Round 2
// 1857.922 us; speedup vs baseline: 1.3865x; 1.3865x over previous
//
#include <hip/hip_runtime.h>
#include <hip/hip_bf16.h>
#include <math.h>

// MoE: B=4,S=2048 -> T=8192 tokens, D=2048, E=8 experts, F=2048, top-2.
#define T_TOK 8192
#define DDIM  2048
#define NEXP  8
#define FDIM  2048
#define BK    32

typedef __bf16 bf16x8 __attribute__((ext_vector_type(8)));
typedef float  f32x4  __attribute__((ext_vector_type(4)));

#define MFMA16(a, b, c) __builtin_amdgcn_mfma_f32_16x16x32_bf16((a), (b), (c), 0, 0, 0)

// async global->LDS, 16B per lane; LDS dest = wave-uniform base + lane*16
#define GLDS16(g, l)                                                            \
  __builtin_amdgcn_global_load_lds(                                             \
      (const __attribute__((address_space(1))) void*)(g),                       \
      (__attribute__((address_space(3))) void*)(l), 16, 0, 0)

__device__ __forceinline__ unsigned short f2bf(float f) {
  unsigned int u = __builtin_bit_cast(unsigned int, f);
  u += 0x7fffu + ((u >> 16) & 1u);
  return (unsigned short)(u >> 16);
}

// ---------------- fp32 -> bf16 bulk convert (8 elems/thread, grid-stride) ----
__global__ __launch_bounds__(256) void k_cvt(const float* __restrict__ src,
                                             unsigned short* __restrict__ dst,
                                             long n) {
  long i = ((long)blockIdx.x * 256 + threadIdx.x) * 8;
  long stride = (long)gridDim.x * 256 * 8;
  for (; i < n; i += stride) {
    float4 f0 = *(const float4*)(src + i);
    float4 f1 = *(const float4*)(src + i + 4);
    union { unsigned short u[8]; int4 v; } pk;
    pk.u[0] = f2bf(f0.x); pk.u[1] = f2bf(f0.y); pk.u[2] = f2bf(f0.z); pk.u[3] = f2bf(f0.w);
    pk.u[4] = f2bf(f1.x); pk.u[5] = f2bf(f1.y); pk.u[6] = f2bf(f1.z); pk.u[7] = f2bf(f1.w);
    *(int4*)(dst + i) = pk.v;
  }
}

// ---------------- router: fp32 logits -> softmax -> top2 ----------------
__global__ __launch_bounds__(256) void k_router(
    const float* __restrict__ x, const float* __restrict__ gw,
    int* __restrict__ cnt, int* __restrict__ topk_e, float* __restrict__ topk_w) {
  int lane = threadIdx.x & 63;
  int wave = threadIdx.x >> 6;
  int t = blockIdx.x * 4 + wave;
  const float* xr = x + (size_t)t * DDIM;
  float acc[NEXP];
#pragma unroll
  for (int e = 0; e < NEXP; e++) acc[e] = 0.f;
  for (int j = lane; j < DDIM; j += 64) {
    float xv = xr[j];
#pragma unroll
    for (int e = 0; e < NEXP; e++) acc[e] += xv * gw[e * DDIM + j];
  }
#pragma unroll
  for (int e = 0; e < NEXP; e++) {
    for (int off = 32; off > 0; off >>= 1) acc[e] += __shfl_down(acc[e], off, 64);
  }
  if (lane == 0) {
    float m = acc[0];
#pragma unroll
    for (int e = 1; e < NEXP; e++) m = fmaxf(m, acc[e]);
    float p[NEXP]; float s = 0.f;
#pragma unroll
    for (int e = 0; e < NEXP; e++) { p[e] = expf(acc[e] - m); s += p[e]; }
    float inv = 1.f / s;
    int e1 = 0; float v1 = p[0];
#pragma unroll
    for (int e = 1; e < NEXP; e++) if (p[e] > v1) { v1 = p[e]; e1 = e; }
    int e2 = -1; float v2 = -1.f;
#pragma unroll
    for (int e = 0; e < NEXP; e++) {
      if (e == e1) continue;
      if (p[e] > v2) { v2 = p[e]; e2 = e; }
    }
    topk_e[t * 2 + 0] = e1; topk_w[t * 2 + 0] = v1 * inv;
    topk_e[t * 2 + 1] = e2; topk_w[t * 2 + 1] = v2 * inv;
    atomicAdd(&cnt[e1], 1);
    atomicAdd(&cnt[e2], 1);
  }
}

__global__ void k_scan(const int* __restrict__ cnt, int* __restrict__ prefix) {
  if (threadIdx.x == 0 && blockIdx.x == 0) {
    int s = 0;
    for (int e = 0; e < NEXP; e++) { prefix[e] = s; s += cnt[e]; }
    prefix[NEXP] = s;
  }
}

// After computing the slot, the slot index is written back into topk_e storage
// (read-before-write within the same thread/index), so k_combine can gather
// the two expert-output rows per token.
__global__ __launch_bounds__(256) void k_assign(
    int* __restrict__ topk_e, const float* __restrict__ topk_w,
    const int* __restrict__ prefix, int* __restrict__ fill,
    int* __restrict__ toks, float* __restrict__ rwc) {
  int t = blockIdx.x * 256 + threadIdx.x;
  if (t >= T_TOK) return;
#pragma unroll
  for (int k = 0; k < 2; k++) {
    int e = topk_e[t * 2 + k];
    float w = topk_w[t * 2 + k];
    int pos = atomicAdd(&fill[e], 1);
    int slot = prefix[e] + pos;
    toks[slot] = t;
    rwc[slot] = w;
    topk_e[t * 2 + k] = slot;   // repurpose as slot_of[t][k]
  }
}

// ---------------- GEMM1: H = silu(X W1^T) * (X W3^T), 128x64 tile ------------
// A = gathered token rows (bf16), B1/B3 = w1/w3 rows (bf16). global_load_lds
// staging, unpadded LDS [row][32] (m97 recipe). Dual accumulators share A-frags.
__global__ __launch_bounds__(256) void k_gemm1(
    const unsigned short* __restrict__ xb, const unsigned short* __restrict__ w1b,
    const unsigned short* __restrict__ w3b, const int* __restrict__ cnt,
    const int* __restrict__ prefix, const int* __restrict__ toks,
    unsigned short* __restrict__ hbuf) {
  int e  = blockIdx.x >> 6;   // 64 m-blocks per expert (worst case 8192/128)
  int mb = blockIdx.x & 63;
  int ne = cnt[e];
  if (mb * 128 >= ne) return;
  int base = prefix[e];
  int fb = blockIdx.y;        // F/64

  __shared__ __align__(16) unsigned short As[128 * BK];
  __shared__ __align__(16) unsigned short B1s[64 * BK];
  __shared__ __align__(16) unsigned short B3s[64 * BK];
  __shared__ int ltok[128];

  int tid = threadIdx.x;
  if (tid < 128) {
    int i = mb * 128 + tid;
    ltok[tid] = (i < ne) ? toks[base + i] : 0;  // pad rows read token 0 (masked at store)
  }
  __syncthreads();

  int lane = tid & 63;
  int wv = tid >> 6;

  // staging: 16 segments of 16 rows x 64B. waves 0,1 -> A; wave 2 -> B1; wave 3 -> B3.
  int r_in_seg = lane >> 2;       // 0..15
  int c16 = (lane & 3) * 8;       // bf16 col offset 0,8,16,24
  const unsigned short* gsrc[4];
  unsigned short* ldst[4];
#pragma unroll
  for (int i = 0; i < 4; i++) {
    if (wv < 2) {
      int row = (wv * 4 + i) * 16 + r_in_seg;   // 0..127
      gsrc[i] = xb + (size_t)ltok[row] * DDIM + c16;
      ldst[i] = (unsigned short*)As + (wv * 4 + i) * 16 * BK;
    } else if (wv == 2) {
      int row = i * 16 + r_in_seg;              // 0..63
      gsrc[i] = w1b + ((size_t)e * FDIM + fb * 64 + row) * DDIM + c16;
      ldst[i] = (unsigned short*)B1s + i * 16 * BK;
    } else {
      int row = i * 16 + r_in_seg;
      gsrc[i] = w3b + ((size_t)e * FDIM + fb * 64 + row) * DDIM + c16;
      ldst[i] = (unsigned short*)B3s + i * 16 * BK;
    }
  }

  int fr = lane & 15;
  int q  = lane >> 4;
  int wm = (wv >> 1) * 64;   // wave grid 2x2: {0,64} x {0,32}
  int wn = (wv & 1) * 32;

  f32x4 accG[4][2], accU[4][2];
#pragma unroll
  for (int i = 0; i < 4; i++)
#pragma unroll
    for (int j = 0; j < 2; j++) { accG[i][j] = (f32x4){0,0,0,0}; accU[i][j] = (f32x4){0,0,0,0}; }

  for (int k0 = 0; k0 < DDIM; k0 += BK) {
#pragma unroll
    for (int i = 0; i < 4; i++) GLDS16(gsrc[i] + k0, ldst[i]);
    __syncthreads();

    bf16x8 af[4], b1f[2], b3f[2];
#pragma unroll
    for (int sm = 0; sm < 4; sm++)
      af[sm] = *(const bf16x8*)(As + (wm + sm * 16 + fr) * BK + q * 8);
#pragma unroll
    for (int sn = 0; sn < 2; sn++) {
      b1f[sn] = *(const bf16x8*)(B1s + (wn + sn * 16 + fr) * BK + q * 8);
      b3f[sn] = *(const bf16x8*)(B3s + (wn + sn * 16 + fr) * BK + q * 8);
    }
#pragma unroll
    for (int sm = 0; sm < 4; sm++)
#pragma unroll
      for (int sn = 0; sn < 2; sn++) {
        accG[sm][sn] = MFMA16(af[sm], b1f[sn], accG[sm][sn]);
        accU[sm][sn] = MFMA16(af[sm], b3f[sn], accU[sm][sn]);
      }
    __syncthreads();
  }

#pragma unroll
  for (int sm = 0; sm < 4; sm++)
#pragma unroll
    for (int sn = 0; sn < 2; sn++)
#pragma unroll
      for (int r = 0; r < 4; r++) {
        int row = mb * 128 + wm + sm * 16 + q * 4 + r;
        if (row < ne) {
          int col = fb * 64 + wn + sn * 16 + fr;
          float g = accG[sm][sn][r];
          float u = accU[sm][sn][r];
          float h = (g / (1.f + expf(-g))) * u;
          hbuf[(size_t)(base + row) * FDIM + col] = f2bf(h);
        }
      }
}

// ---------------- GEMM2: Z[slot] = H[slot] W2^T, 128x128 tile ----------------
// Plain f32 stores to ybuf (one row per slot); top-2 combine happens in
// k_combine. No atomics, no token/weight gather needed here.
__global__ __launch_bounds__(256) void k_gemm2(
    const unsigned short* __restrict__ hbuf, const unsigned short* __restrict__ w2b,
    const int* __restrict__ cnt, const int* __restrict__ prefix,
    float* __restrict__ ybuf) {
  int e  = blockIdx.x >> 6;
  int mb = blockIdx.x & 63;
  int ne = cnt[e];
  if (mb * 128 >= ne) return;
  int base = prefix[e];
  int db = blockIdx.y;   // D/128

  __shared__ __align__(16) unsigned short As[128 * BK];
  __shared__ __align__(16) unsigned short Bs[128 * BK];

  int tid = threadIdx.x;
  int lane = tid & 63;
  int wv = tid >> 6;
  int r_in_seg = lane >> 2;
  int c16 = (lane & 3) * 8;
  const unsigned short* gsrc[4];
  unsigned short* ldst[4];
#pragma unroll
  for (int i = 0; i < 4; i++) {
    int seg = wv * 4 + i;
    if (seg < 8) {
      int row = seg * 16 + r_in_seg;            // 0..127, contiguous hbuf slots
      gsrc[i] = hbuf + (size_t)(base + mb * 128 + row) * FDIM + c16;
      ldst[i] = (unsigned short*)As + seg * 16 * BK;
    } else {
      int row = (seg - 8) * 16 + r_in_seg;      // 0..127
      gsrc[i] = w2b + ((size_t)e * DDIM + db * 128 + row) * FDIM + c16;
      ldst[i] = (unsigned short*)Bs + (seg - 8) * 16 * BK;
    }
  }

  int fr = lane & 15;
  int q  = lane >> 4;
  int wm = (wv >> 1) * 64;   // wave grid 2x2: 64x64 per wave
  int wn = (wv & 1) * 64;

  f32x4 acc[4][4];
#pragma unroll
  for (int i = 0; i < 4; i++)
#pragma unroll
    for (int j = 0; j < 4; j++) acc[i][j] = (f32x4){0,0,0,0};

  for (int k0 = 0; k0 < FDIM; k0 += BK) {
#pragma unroll
    for (int i = 0; i < 4; i++) GLDS16(gsrc[i] + k0, ldst[i]);
    __syncthreads();

    bf16x8 af[4], bf[4];
#pragma unroll
    for (int sm = 0; sm < 4; sm++)
      af[sm] = *(const bf16x8*)(As + (wm + sm * 16 + fr) * BK + q * 8);
#pragma unroll
    for (int sn = 0; sn < 4; sn++)
      bf[sn] = *(const bf16x8*)(Bs + (wn + sn * 16 + fr) * BK + q * 8);
#pragma unroll
    for (int sm = 0; sm < 4; sm++)
#pragma unroll
      for (int sn = 0; sn < 4; sn++)
        acc[sm][sn] = MFMA16(af[sm], bf[sn], acc[sm][sn]);
    __syncthreads();
  }

#pragma unroll
  for (int sm = 0; sm < 4; sm++)
#pragma unroll
    for (int sn = 0; sn < 4; sn++)
#pragma unroll
      for (int r = 0; r < 4; r++) {
        int lrow = wm + sm * 16 + q * 4 + r;
        int row = mb * 128 + lrow;
        if (row < ne) {
          int col = db * 128 + wn + sn * 16 + fr;
          ybuf[(size_t)(base + row) * DDIM + col] = acc[sm][sn][r];
        }
      }
}

// ---------------- combine: y[t] = w0*ybuf[s0] + w1*ybuf[s1] ------------------
__global__ __launch_bounds__(256) void k_combine(
    const float* __restrict__ ybuf, const int* __restrict__ slt,
    const float* __restrict__ rwc, float* __restrict__ y) {
  int t = blockIdx.x;                      // 8192 tokens
  int s0 = slt[2 * t + 0];
  int s1 = slt[2 * t + 1];
  float w0 = rwc[s0];
  float w1 = rwc[s1];
  const float4* r0 = (const float4*)(ybuf + (size_t)s0 * DDIM);
  const float4* r1 = (const float4*)(ybuf + (size_t)s1 * DDIM);
  float4* yo = (float4*)(y + (size_t)t * DDIM);
#pragma unroll
  for (int it = 0; it < 2; it++) {
    int i = it * 256 + threadIdx.x;        // DDIM/4 = 512
    float4 a = r0[i], b = r1[i], o;
    o.x = w0 * a.x + w1 * b.x;
    o.y = w0 * a.y + w1 * b.y;
    o.z = w0 * a.z + w1 * b.z;
    o.w = w0 * a.w + w1 * b.w;
    yo[i] = o;
  }
}

// ---------------- launch ----------------
// ws layout (bytes), 16B-aligned chunks:
//   0          cnt[8] / 256 fill[8] / 512 prefix[9]
//   1024       topk_e[16384] -> reused as slot_of after k_assign   (64 KiB)
//   66560      topk_w[16384]            (64 KiB)
//   132096     toks[16384]              (64 KiB)
//   197632     rwc[16384]               (64 KiB)
//   263168     hbuf: 16512 x 2048 bf16  (67.6 MB; +128 pad rows for tile overrun)
//   67896320   w1b bf16                 (67.1 MB)  \ after gemm1 these two are dead;
//   135005184  w3b bf16                 (67.1 MB)  / ybuf f32 (16384x2048 = 134.2 MB)
//                                                    overlays [67896320, 202114048)
//   202114048  w2b bf16                 (67.1 MB)
//   269222912  xb  bf16                 (33.6 MB)   total ~302.8 MB
extern "C" void kernel_launch(void* const* d_in, const int* in_sizes, int n_in,
                              void* d_out, int out_size, void* d_ws, size_t ws_size,
                              hipStream_t stream) {
  const float* x  = (const float*)d_in[0];
  const float* gw = (const float*)d_in[1];
  const float* w1 = (const float*)d_in[2];
  const float* w3 = (const float*)d_in[3];
  const float* w2 = (const float*)d_in[4];
  float* y = (float*)d_out;

  char* ws = (char*)d_ws;
  int*   cnt    = (int*)(ws + 0);
  int*   fill   = (int*)(ws + 256);
  int*   prefix = (int*)(ws + 512);
  int*   topk_e = (int*)(ws + 1024);
  float* topk_w = (float*)(ws + 66560);
  int*   toks   = (int*)(ws + 132096);
  float* rwc    = (float*)(ws + 197632);
  unsigned short* hbuf = (unsigned short*)(ws + 263168);
  unsigned short* w1b  = (unsigned short*)(ws + 67896320UL);
  unsigned short* w3b  = (unsigned short*)(ws + 135005184UL);
  unsigned short* w2b  = (unsigned short*)(ws + 202114048UL);
  unsigned short* xb   = (unsigned short*)(ws + 269222912UL);
  float* ybuf = (float*)(ws + 67896320UL);   // overlays w1b+w3b (dead after gemm1)

  const long NW = (long)NEXP * FDIM * DDIM;   // 33.55M per weight tensor
  const long NX = (long)T_TOK * DDIM;         // 16.78M

  hipMemsetAsync(ws, 0, 1024, stream);
  // no d_out memset: k_combine fully overwrites y

  k_cvt<<<1024, 256, 0, stream>>>(w1, w1b, NW);
  k_cvt<<<1024, 256, 0, stream>>>(w3, w3b, NW);
  k_cvt<<<1024, 256, 0, stream>>>(w2, w2b, NW);
  k_cvt<<<1024, 256, 0, stream>>>(x,  xb,  NX);

  k_router<<<T_TOK / 4, 256, 0, stream>>>(x, gw, cnt, topk_e, topk_w);
  k_scan<<<1, 64, 0, stream>>>(cnt, prefix);
  k_assign<<<T_TOK / 256, 256, 0, stream>>>(topk_e, topk_w, prefix, fill, toks, rwc);

  k_gemm1<<<dim3(NEXP * 64, FDIM / 64), 256, 0, stream>>>(xb, w1b, w3b, cnt, prefix, toks, hbuf);
  k_gemm2<<<dim3(NEXP * 64, DDIM / 128), 256, 0, stream>>>(hbuf, w2b, cnt, prefix, ybuf);
  k_combine<<<T_TOK, 256, 0, stream>>>(ybuf, topk_e, rwc, y);
}